// Round 1
// baseline (427.753 us; speedup 1.0000x reference)
//
#include <hip/hip_runtime.h>

// Z gate with DIM=2, S=1, INDEX=(0,5,10), L=14  =>  phase = (-1)^(d13^d8^d3 of n)
// out[0]  = sign(n) * x_real   (N*B floats)
// out[1]  = sign(n) * x_imag   (N*B floats)
// Flat element index e = n*B + b, B=2048 => sign bits live at e-bits 14, 19, 24.
// Pure streaming kernel: float4 loads/stores, one parity calc per thread.

#define NB_TOTAL (16384LL * 2048LL)   // N*B = 33,554,432 elements per array
#define NVEC     ((int)(NB_TOTAL / 4))  // 8,388,608 float4 per array

__global__ __launch_bounds__(256) void z_phase_kernel(
    const float4* __restrict__ xr,
    const float4* __restrict__ xi,
    float4* __restrict__ outr,
    float4* __restrict__ outi)
{
    int i = blockIdx.x * blockDim.x + threadIdx.x;
    if (i >= NVEC) return;

    // element index = 4*i; sign-controlling bits of e at 14,19,24
    // => bits 12,17,22 of i (since e = i<<2)
    unsigned int u = (unsigned int)i;
    unsigned int par = ((u >> 12) ^ (u >> 17) ^ (u >> 22)) & 1u;
    // sign-flip via sign-bit XOR (no FP multiply needed)
    unsigned int flip = par << 31;

    float4 r = xr[i];
    float4 m = xi[i];

    union { float f; unsigned int u; } c;
    c.f = r.x; c.u ^= flip; r.x = c.f;
    c.f = r.y; c.u ^= flip; r.y = c.f;
    c.f = r.z; c.u ^= flip; r.z = c.f;
    c.f = r.w; c.u ^= flip; r.w = c.f;
    c.f = m.x; c.u ^= flip; m.x = c.f;
    c.f = m.y; c.u ^= flip; m.y = c.f;
    c.f = m.z; c.u ^= flip; m.z = c.f;
    c.f = m.w; c.u ^= flip; m.w = c.f;

    outr[i] = r;
    outi[i] = m;
}

extern "C" void kernel_launch(void* const* d_in, const int* in_sizes, int n_in,
                              void* d_out, int out_size, void* d_ws, size_t ws_size,
                              hipStream_t stream) {
    const float4* xr = (const float4*)d_in[0];
    const float4* xi = (const float4*)d_in[1];
    float4* outr = (float4*)d_out;                     // first N*B floats
    float4* outi = (float4*)((float*)d_out + NB_TOTAL); // next N*B floats

    const int block = 256;
    const int grid = (NVEC + block - 1) / block;  // 32768 blocks
    z_phase_kernel<<<grid, block, 0, stream>>>(xr, xi, outr, outi);
}